// Round 2
// baseline (2965.338 us; speedup 1.0000x reference)
//
#include <hip/hip_runtime.h>

// ---------------------------------------------------------------------------
// BidirRecurrentModel: 2-layer bidirectional GRU (both layers read raw x).
// ALL inputs/outputs are FLOAT32 (per reference setup_inputs). Internally:
//   Phase 1: gx[b][l][t][g] = sum_d x[b,t,d]*Wx[l,g,d] + bx[l,g]
//            fp32 -> fp16 convert on the fly, f16 MFMA, gx stored fp16 in ws.
//   Phase 2: 128 independent chains (b,l,dir), sequential over T=2048.
//            Wh register-resident as fp16x2, dots via v_dot2_f32_f16,
//            h carried fp32, output stored fp32.
// ---------------------------------------------------------------------------

typedef _Float16 half8 __attribute__((ext_vector_type(8)));
typedef _Float16 half2_t __attribute__((ext_vector_type(2)));
typedef float floatx4 __attribute__((ext_vector_type(4)));

__device__ __forceinline__ float sigmoidf_fast(float x) {
    return 1.0f / (1.0f + __expf(-x));
}

__device__ __forceinline__ float tanh_fast(float x) {
    float ax = fabsf(x);
    float e = __expf(-2.0f * ax);
    float t = (1.0f - e) / (1.0f + e);
    return copysignf(t, x);
}

// ---------------------------------------------------------------------------
// Kernel 1: gx GEMM.  C[M=65536][N=1536] = x[M][256] * Wx[N][256]^T + bx[N]
// 128x128 tile per block (4 waves, each 64x64 via 4x4 of 16x16x32 f16 MFMA).
// LDS layout [kchunk][row][8] halves so frag ds_read_b128 is conflict-free.
// Output scattered to gx[b][l][t][768] fp16 via LDS epilogue (coalesced).
// ---------------------------------------------------------------------------
__global__ __launch_bounds__(256) void gemm_gx_kernel(
    const float* __restrict__ x,
    const float* __restrict__ Wx,
    const float* __restrict__ bx,
    _Float16* __restrict__ gx)
{
    __shared__ __align__(16) char lds[32768];
    _Float16* As = (_Float16*)lds;            // [4][128][8] fp16 (8 KB)
    _Float16* Bs = (_Float16*)(lds + 8192);   // [4][128][8] fp16 (8 KB)

    const int tid = threadIdx.x;
    const int m0 = blockIdx.x * 128;
    const int n0 = blockIdx.y * 128;
    const int wave = tid >> 6;
    const int lane = tid & 63;
    const int wm = wave & 1;
    const int wn = wave >> 1;
    const int frag = lane & 15;
    const int kg = lane >> 4;

    floatx4 acc[4][4];
#pragma unroll
    for (int a = 0; a < 4; ++a)
#pragma unroll
        for (int b = 0; b < 4; ++b)
            acc[a][b] = (floatx4){0.f, 0.f, 0.f, 0.f};

    for (int k0 = 0; k0 < 256; k0 += 32) {
        __syncthreads();
#pragma unroll
        for (int rep = 0; rep < 2; ++rep) {
            int idx = tid + rep * 256;   // 512 slots of 8 elems = 128x32 tile
            int row = idx >> 2;
            int kc = idx & 3;
            const float4* ap = (const float4*)(x + (size_t)(m0 + row) * 256 + k0 + kc * 8);
            const float4* bp = (const float4*)(Wx + (size_t)(n0 + row) * 256 + k0 + kc * 8);
            float4 a0 = ap[0], a1 = ap[1];
            float4 b0 = bp[0], b1 = bp[1];
            half8 av = {(_Float16)a0.x, (_Float16)a0.y, (_Float16)a0.z, (_Float16)a0.w,
                        (_Float16)a1.x, (_Float16)a1.y, (_Float16)a1.z, (_Float16)a1.w};
            half8 bv = {(_Float16)b0.x, (_Float16)b0.y, (_Float16)b0.z, (_Float16)b0.w,
                        (_Float16)b1.x, (_Float16)b1.y, (_Float16)b1.z, (_Float16)b1.w};
            *(half8*)(As + (kc * 128 + row) * 8) = av;
            *(half8*)(Bs + (kc * 128 + row) * 8) = bv;
        }
        __syncthreads();

        half8 af[4], bfr[4];
#pragma unroll
        for (int tm = 0; tm < 4; ++tm)
            af[tm] = *(const half8*)(As + (kg * 128 + wm * 64 + tm * 16 + frag) * 8);
#pragma unroll
        for (int tn = 0; tn < 4; ++tn)
            bfr[tn] = *(const half8*)(Bs + (kg * 128 + wn * 64 + tn * 16 + frag) * 8);
#pragma unroll
        for (int tm = 0; tm < 4; ++tm)
#pragma unroll
            for (int tn = 0; tn < 4; ++tn)
                acc[tm][tn] = __builtin_amdgcn_mfma_f32_16x16x32_f16(
                    af[tm], bfr[tn], acc[tm][tn], 0, 0, 0);
    }

    __syncthreads();
    // Epilogue: bias add, fp16 convert, re-layout via LDS for coalesced stores.
    _Float16* epi = (_Float16*)lds;  // [128][128]
#pragma unroll
    for (int tm = 0; tm < 4; ++tm) {
#pragma unroll
        for (int tn = 0; tn < 4; ++tn) {
            int col = wn * 64 + tn * 16 + frag;
            float bias = bx[n0 + col];
#pragma unroll
            for (int r = 0; r < 4; ++r) {
                int rowc = wm * 64 + tm * 16 + kg * 4 + r;  // C/D: col=lane&15, row=quad*4+reg
                epi[rowc * 128 + col] = (_Float16)(acc[tm][tn][r] + bias);
            }
        }
    }
    __syncthreads();

    // copy out: each thread -> 64 contiguous fp16 of one row
    int row = tid >> 1;
    int hs = tid & 1;
    int gm = m0 + row;
    int bb = gm >> 11;          // batch
    int tt = gm & 2047;         // time
    int l = n0 / 768;           // 768 % 128 == 0, so a block never crosses l
    int g0 = n0 - l * 768 + hs * 64;
    size_t oidx = (((size_t)bb * 2 + l) * 2048 + tt) * 768 + g0;
    const uint4* s = (const uint4*)(epi + row * 128 + hs * 64);
    uint4* d = (uint4*)(gx + oidx);
#pragma unroll
    for (int j = 0; j < 8; ++j) d[j] = s[j];
}

// ---------------------------------------------------------------------------
// Kernel 2: the recurrence. One block per chain (b, l, dir); 128 blocks.
// 512 threads: i = tid&255 (output unit), q = tid>>8 (k-half).
// Each thread holds Wh rows {i, 256+i, 512+i}, cols [q*128, q*128+128) as
// 192 packed fp16x2 VGPRs. h carried fp32 in gate-thread registers; fp16
// copy in LDS for the dot phase. gx double-buffered in LDS (prefetch t+1).
//
// R1 change (resubmitted after infra failure): __launch_bounds__(512, 2) ->
// (512, 1). HIP launch_bounds 2nd arg = min BLOCKS/CU (CUDA semantics):
// (512,2) demanded 2 blocks/CU = 4 waves/SIMD -> 128-VGPR cap (matches
// measured VGPR_Count=128) while the weight arrays alone need 192 VGPRs ->
// AGPR/scratch shuffling = the measured 70% per-step stall (VALUBusy 30%).
// With only 128 blocks on 256 CUs, 2 blocks/CU never happens anyway.
// (512,1) -> 2 waves/SIMD -> 256-VGPR cap: weights stay architectural.
// ---------------------------------------------------------------------------
__global__ __launch_bounds__(512, 1) void gru_scan_kernel(
    const float* __restrict__ Wh,
    const float* __restrict__ bh,
    const _Float16* __restrict__ gx,
    float* __restrict__ out)
{
    const int c = blockIdx.x;
    const int b = c & 31;
    const int l = (c >> 5) & 1;
    const int dir = c >> 6;
    const int tid = threadIdx.x;
    const int i = tid & 255;
    const int q = tid >> 8;

    __shared__ __align__(16) _Float16 h2[256];     // fp16 copy of h
    __shared__ float part[3][256];                 // q=1 partial sums
    __shared__ unsigned int gxb[2][384];           // gx_t double buffer (768 fp16)

    // --- load Wh into registers, converting fp32 -> fp16x2 (one-time) ---
    half2_t wr[64], wz[64], wn_[64];
    {
        const float2* pr = (const float2*)(Wh + ((size_t)l * 768 + i) * 256 + q * 128);
        const float2* pz = (const float2*)(Wh + ((size_t)l * 768 + 256 + i) * 256 + q * 128);
        const float2* pn = (const float2*)(Wh + ((size_t)l * 768 + 512 + i) * 256 + q * 128);
#pragma unroll
        for (int j = 0; j < 64; ++j) {
            float2 a = pr[j], bb2 = pz[j], cc = pn[j];
            wr[j]  = (half2_t){(_Float16)a.x, (_Float16)a.y};
            wz[j]  = (half2_t){(_Float16)bb2.x, (_Float16)bb2.y};
            wn_[j] = (half2_t){(_Float16)cc.x, (_Float16)cc.y};
        }
    }

    const float bhr = bh[l * 768 + i];
    const float bhz = bh[l * 768 + 256 + i];
    const float bhn = bh[l * 768 + 512 + i];

    const unsigned int* gxrow = (const unsigned int*)gx + (size_t)(b * 2 + l) * 2048 * 384;
    // out flat index: ((b*4096) + t*2 + l)*512 + dir*256 + i
    float* outp = out + (size_t)b * 2048 * 1024 + (size_t)l * 512 + dir * 256 + i;

    if (tid < 256) h2[tid] = (_Float16)0.f;
    {
        int t0 = dir ? 2047 : 0;
        if (tid < 384) gxb[0][tid] = gxrow[(size_t)t0 * 384 + tid];
    }
    __syncthreads();

    float hreg = 0.f;

    for (int s = 0; s < 2048; ++s) {
        const int t = dir ? (2047 - s) : s;
        const int sn = (s < 2047) ? (s + 1) : s;
        const int tn = dir ? (2047 - sn) : sn;

        // prefetch next step's gx row (latency hidden behind dot phase)
        unsigned int pf = 0;
        if (tid < 384) pf = gxrow[(size_t)tn * 384 + tid];

        // --- dot phase: 3 gates x 128 k-elems = 192 v_dot2 per thread ---
        float ar = 0.f, az = 0.f, an = 0.f;
        const half2_t* hp = ((const half2_t*)h2) + q * 64;
#pragma unroll
        for (int j = 0; j < 64; ++j) {
            half2_t hv = hp[j];   // wave-uniform address -> LDS broadcast
            ar = __builtin_amdgcn_fdot2(wr[j], hv, ar, false);
            az = __builtin_amdgcn_fdot2(wz[j], hv, az, false);
            an = __builtin_amdgcn_fdot2(wn_[j], hv, an, false);
        }
        if (q) { part[0][i] = ar; part[1][i] = az; part[2][i] = an; }
        __syncthreads();

        if (tid < 256) {
            float ghr = ar + part[0][i] + bhr;
            float ghz = az + part[1][i] + bhz;
            float ghn = an + part[2][i] + bhn;
            const _Float16* gxc = (const _Float16*)(&gxb[s & 1][0]);
            float xr = (float)gxc[i];
            float xz = (float)gxc[256 + i];
            float xn = (float)gxc[512 + i];
            float r = sigmoidf_fast(xr + ghr);
            float z = sigmoidf_fast(xz + ghz);
            float n = tanh_fast(xn + r * ghn);
            float hnew = (1.f - z) * n + z * hreg;
            hreg = hnew;
            outp[(size_t)t * 1024] = hnew;
            h2[i] = (_Float16)hnew;
        }
        if (tid < 384) gxb[sn & 1][tid] = pf;  // s=2047: rewrites identical values (benign)
        __syncthreads();
    }
}

// ---------------------------------------------------------------------------
extern "C" void kernel_launch(void* const* d_in, const int* in_sizes, int n_in,
                              void* d_out, int out_size, void* d_ws, size_t ws_size,
                              hipStream_t stream) {
    const float* x  = (const float*)d_in[0];  // (32,2048,256) fp32
    const float* Wx = (const float*)d_in[1];  // (2,768,256)  fp32
    const float* Wh = (const float*)d_in[2];  // (2,768,256)  fp32
    const float* bx = (const float*)d_in[3];  // (2,768)      fp32
    const float* bh = (const float*)d_in[4];  // (2,768)      fp32
    float* out = (float*)d_out;               // (32,4096,512) fp32
    _Float16* gxbuf = (_Float16*)d_ws;        // 100,663,296 fp16 = 201.3 MB

    // Phase 1: gx = x @ Wx^T + bx  (layout [b][l][t][768], fp16)
    gemm_gx_kernel<<<dim3(512, 12), 256, 0, stream>>>(x, Wx, bx, gxbuf);

    // Phase 2: 128 independent (b, l, dir) GRU chains
    gru_scan_kernel<<<dim3(128), 512, 0, stream>>>(Wh, bh, gxbuf, out);
}

// Round 3
// 2880.690 us; speedup vs baseline: 1.0294x; 1.0294x over previous
//
#include <hip/hip_runtime.h>

// ---------------------------------------------------------------------------
// BidirRecurrentModel: 2-layer bidirectional GRU (both layers read raw x).
// ALL inputs/outputs are FLOAT32 (per reference setup_inputs). Internally:
//   Phase 1: gx[b][l][t][g] = sum_d x[b,t,d]*Wx[l,g,d] + bx[l,g]
//            fp32 -> fp16 convert on the fly, f16 MFMA, gx stored fp16 in ws.
//   Phase 2: 128 independent chains (b,l,dir), sequential over T=2048.
// ---------------------------------------------------------------------------

typedef _Float16 half8 __attribute__((ext_vector_type(8)));
typedef _Float16 half2_t __attribute__((ext_vector_type(2)));
typedef float floatx4 __attribute__((ext_vector_type(4)));

__device__ __forceinline__ float sigmoidf_fast(float x) {
    return 1.0f / (1.0f + __expf(-x));
}

__device__ __forceinline__ float tanh_fast(float x) {
    float ax = fabsf(x);
    float e = __expf(-2.0f * ax);
    float t = (1.0f - e) / (1.0f + e);
    return copysignf(t, x);
}

// ---------------------------------------------------------------------------
// Kernel 1: gx GEMM.  C[M=65536][N=1536] = x[M][256] * Wx[N][256]^T + bx[N]
// (unchanged — ~300 us, not the bottleneck)
// ---------------------------------------------------------------------------
__global__ __launch_bounds__(256) void gemm_gx_kernel(
    const float* __restrict__ x,
    const float* __restrict__ Wx,
    const float* __restrict__ bx,
    _Float16* __restrict__ gx)
{
    __shared__ __align__(16) char lds[32768];
    _Float16* As = (_Float16*)lds;            // [4][128][8] fp16 (8 KB)
    _Float16* Bs = (_Float16*)(lds + 8192);   // [4][128][8] fp16 (8 KB)

    const int tid = threadIdx.x;
    const int m0 = blockIdx.x * 128;
    const int n0 = blockIdx.y * 128;
    const int wave = tid >> 6;
    const int lane = tid & 63;
    const int wm = wave & 1;
    const int wn = wave >> 1;
    const int frag = lane & 15;
    const int kg = lane >> 4;

    floatx4 acc[4][4];
#pragma unroll
    for (int a = 0; a < 4; ++a)
#pragma unroll
        for (int b = 0; b < 4; ++b)
            acc[a][b] = (floatx4){0.f, 0.f, 0.f, 0.f};

    for (int k0 = 0; k0 < 256; k0 += 32) {
        __syncthreads();
#pragma unroll
        for (int rep = 0; rep < 2; ++rep) {
            int idx = tid + rep * 256;   // 512 slots of 8 elems = 128x32 tile
            int row = idx >> 2;
            int kc = idx & 3;
            const float4* ap = (const float4*)(x + (size_t)(m0 + row) * 256 + k0 + kc * 8);
            const float4* bp = (const float4*)(Wx + (size_t)(n0 + row) * 256 + k0 + kc * 8);
            float4 a0 = ap[0], a1 = ap[1];
            float4 b0 = bp[0], b1 = bp[1];
            half8 av = {(_Float16)a0.x, (_Float16)a0.y, (_Float16)a0.z, (_Float16)a0.w,
                        (_Float16)a1.x, (_Float16)a1.y, (_Float16)a1.z, (_Float16)a1.w};
            half8 bv = {(_Float16)b0.x, (_Float16)b0.y, (_Float16)b0.z, (_Float16)b0.w,
                        (_Float16)b1.x, (_Float16)b1.y, (_Float16)b1.z, (_Float16)b1.w};
            *(half8*)(As + (kc * 128 + row) * 8) = av;
            *(half8*)(Bs + (kc * 128 + row) * 8) = bv;
        }
        __syncthreads();

        half8 af[4], bfr[4];
#pragma unroll
        for (int tm = 0; tm < 4; ++tm)
            af[tm] = *(const half8*)(As + (kg * 128 + wm * 64 + tm * 16 + frag) * 8);
#pragma unroll
        for (int tn = 0; tn < 4; ++tn)
            bfr[tn] = *(const half8*)(Bs + (kg * 128 + wn * 64 + tn * 16 + frag) * 8);
#pragma unroll
        for (int tm = 0; tm < 4; ++tm)
#pragma unroll
            for (int tn = 0; tn < 4; ++tn)
                acc[tm][tn] = __builtin_amdgcn_mfma_f32_16x16x32_f16(
                    af[tm], bfr[tn], acc[tm][tn], 0, 0, 0);
    }

    __syncthreads();
    // Epilogue: bias add, fp16 convert, re-layout via LDS for coalesced stores.
    _Float16* epi = (_Float16*)lds;  // [128][128]
#pragma unroll
    for (int tm = 0; tm < 4; ++tm) {
#pragma unroll
        for (int tn = 0; tn < 4; ++tn) {
            int col = wn * 64 + tn * 16 + frag;
            float bias = bx[n0 + col];
#pragma unroll
            for (int r = 0; r < 4; ++r) {
                int rowc = wm * 64 + tm * 16 + kg * 4 + r;  // C/D: col=lane&15, row=quad*4+reg
                epi[rowc * 128 + col] = (_Float16)(acc[tm][tn][r] + bias);
            }
        }
    }
    __syncthreads();

    // copy out: each thread -> 64 contiguous fp16 of one row
    int row = tid >> 1;
    int hs = tid & 1;
    int gm = m0 + row;
    int bb = gm >> 11;          // batch
    int tt = gm & 2047;         // time
    int l = n0 / 768;           // 768 % 128 == 0, so a block never crosses l
    int g0 = n0 - l * 768 + hs * 64;
    size_t oidx = (((size_t)bb * 2 + l) * 2048 + tt) * 768 + g0;
    const uint4* s = (const uint4*)(epi + row * 128 + hs * 64);
    uint4* d = (uint4*)(gx + oidx);
#pragma unroll
    for (int j = 0; j < 8; ++j) d[j] = s[j];
}

// ---------------------------------------------------------------------------
// Kernel 2: the recurrence. One block per chain (b, l, dir); 128 blocks.
// R3 restructure:
//  * amdgpu_waves_per_eu(2,2): direct allocator control. R0-R2 showed the
//    allocator pins 128 arch VGPRs regardless of launch_bounds, forcing the
//    192 weight regs into AGPR-shuffles or L2 reloads (60% active-CU VALU
//    busy, 3100 cyc/step vs 768-cyc dot floor). Budget 256 fits all weights.
//  * k-split moved INSIDE the wave: lanes 0-31 handle cols 0-127, lanes
//    32-63 handle cols 128-255 of the SAME output unit i. Reduce via
//    __shfl_xor(.,32) — kills the part[] LDS round-trip and one of the two
//    per-step barriers.
//  * h read from LDS as uint4 (b128): 16 LDS insts/thread/step instead of
//    64; each dword IS a ready half2 dot operand (free bitcast).
//  * h double-buffered (h2[2][256]) so a single end-of-step barrier is
//    race-free (late waves write h[next] while early waves still read h[cur]).
//  * gx consumed straight from registers, prefetched one step ahead
//    (gxb LDS buffer and tid<384 staging removed).
// ---------------------------------------------------------------------------
__global__ __launch_bounds__(512)
__attribute__((amdgpu_waves_per_eu(2, 2)))
void gru_scan_kernel(
    const float* __restrict__ Wh,
    const float* __restrict__ bh,
    const _Float16* __restrict__ gx,
    float* __restrict__ out)
{
    const int c = blockIdx.x;
    const int b = c & 31;
    const int l = (c >> 5) & 1;
    const int dir = c >> 6;
    const int tid = threadIdx.x;
    const int wave = tid >> 6;
    const int lane = tid & 63;
    const int q = lane >> 5;               // k-half: 0 -> cols 0-127, 1 -> 128-255
    const int i = wave * 32 + (lane & 31); // output unit 0..255

    __shared__ __align__(16) _Float16 h2[2][256];  // double-buffered fp16 h

    // --- load Wh into registers, fp32 -> fp16x2 (one-time) ---
    // rows {i, 256+i, 512+i}, cols [q*128, q*128+128)
    half2_t wr[64], wz[64], wn_[64];
    {
        const float2* pr = (const float2*)(Wh + ((size_t)l * 768 + i) * 256 + q * 128);
        const float2* pz = (const float2*)(Wh + ((size_t)l * 768 + 256 + i) * 256 + q * 128);
        const float2* pn = (const float2*)(Wh + ((size_t)l * 768 + 512 + i) * 256 + q * 128);
#pragma unroll
        for (int j = 0; j < 64; ++j) {
            float2 a = pr[j], bb2 = pz[j], cc = pn[j];
            wr[j]  = (half2_t){(_Float16)a.x, (_Float16)a.y};
            wz[j]  = (half2_t){(_Float16)bb2.x, (_Float16)bb2.y};
            wn_[j] = (half2_t){(_Float16)cc.x, (_Float16)cc.y};
        }
    }

    const float bhr = bh[l * 768 + i];
    const float bhz = bh[l * 768 + 256 + i];
    const float bhn = bh[l * 768 + 512 + i];

    const _Float16* gxp = gx + (size_t)(b * 2 + l) * 2048 * 768;
    // out flat index: ((b*4096) + t*2 + l)*512 + dir*256 + i
    float* outp = out + (size_t)b * 2048 * 1024 + (size_t)l * 512 + dir * 256 + i;

    if (tid < 256) h2[0][tid] = (_Float16)0.f;

    // preload gx row for the first step (all lanes: q=0/q=1 read same addr)
    const int t0 = dir ? 2047 : 0;
    _Float16 cxr = gxp[(size_t)t0 * 768 + i];
    _Float16 cxz = gxp[(size_t)t0 * 768 + 256 + i];
    _Float16 cxn = gxp[(size_t)t0 * 768 + 512 + i];
    __syncthreads();

    float hreg = 0.f;

    for (int s = 0; s < 2048; ++s) {
        const int t = dir ? (2047 - s) : s;
        const int sn = (s < 2047) ? (s + 1) : s;
        const int tn = dir ? (2047 - sn) : sn;

        // prefetch next step's gx (hidden behind the dot phase)
        _Float16 pxr = gxp[(size_t)tn * 768 + i];
        _Float16 pxz = gxp[(size_t)tn * 768 + 256 + i];
        _Float16 pxn = gxp[(size_t)tn * 768 + 512 + i];

        // --- dot phase: 3 gates x 64 half2 = 192 v_dot2; h via 16 b128 reads ---
        float ar = 0.f, az = 0.f, an = 0.f;
        const uint4* hbase = (const uint4*)(&h2[s & 1][0]) + (q << 4); // q*256B
#pragma unroll
        for (int j = 0; j < 16; ++j) {
            uint4 hv = hbase[j];
            half2_t h0 = __builtin_bit_cast(half2_t, hv.x);
            half2_t h1 = __builtin_bit_cast(half2_t, hv.y);
            half2_t hg = __builtin_bit_cast(half2_t, hv.z);
            half2_t h3 = __builtin_bit_cast(half2_t, hv.w);
            ar = __builtin_amdgcn_fdot2(wr[4 * j + 0], h0, ar, false);
            az = __builtin_amdgcn_fdot2(wz[4 * j + 0], h0, az, false);
            an = __builtin_amdgcn_fdot2(wn_[4 * j + 0], h0, an, false);
            ar = __builtin_amdgcn_fdot2(wr[4 * j + 1], h1, ar, false);
            az = __builtin_amdgcn_fdot2(wz[4 * j + 1], h1, az, false);
            an = __builtin_amdgcn_fdot2(wn_[4 * j + 1], h1, an, false);
            ar = __builtin_amdgcn_fdot2(wr[4 * j + 2], hg, ar, false);
            az = __builtin_amdgcn_fdot2(wz[4 * j + 2], hg, az, false);
            an = __builtin_amdgcn_fdot2(wn_[4 * j + 2], hg, an, false);
            ar = __builtin_amdgcn_fdot2(wr[4 * j + 3], h3, ar, false);
            az = __builtin_amdgcn_fdot2(wz[4 * j + 3], h3, az, false);
            an = __builtin_amdgcn_fdot2(wn_[4 * j + 3], h3, an, false);
        }

        // cross-half reduction inside the wave (lane i <-> lane i+32)
        ar += __shfl_xor(ar, 32, 64);
        az += __shfl_xor(az, 32, 64);
        an += __shfl_xor(an, 32, 64);

        // --- gate math (all lanes; q=0/q=1 redundantly hold the full sums) ---
        float r = sigmoidf_fast((float)cxr + ar + bhr);
        float z = sigmoidf_fast((float)cxz + az + bhz);
        float n = tanh_fast((float)cxn + an + r * (an * 0.f + (az * 0.f) + (ar * 0.f) + bhn + an - an + (float)0) + 0.f * an);
        // NOTE: expression above must be exactly xn + r*(an_n + bhn); rewritten
        // cleanly below (kept simple to avoid compiler confusion):
        (void)n;
        float ghn = an + bhn;
        n = tanh_fast((float)cxn + r * ghn);
        float hnew = (1.f - z) * n + z * hreg;
        hreg = hnew;

        if (q == 0) {
            outp[(size_t)t * 1024] = hnew;
            h2[(s + 1) & 1][i] = (_Float16)hnew;
        }
        cxr = pxr; cxz = pxz; cxn = pxn;
        __syncthreads();
    }
}

// ---------------------------------------------------------------------------
extern "C" void kernel_launch(void* const* d_in, const int* in_sizes, int n_in,
                              void* d_out, int out_size, void* d_ws, size_t ws_size,
                              hipStream_t stream) {
    const float* x  = (const float*)d_in[0];  // (32,2048,256) fp32
    const float* Wx = (const float*)d_in[1];  // (2,768,256)  fp32
    const float* Wh = (const float*)d_in[2];  // (2,768,256)  fp32
    const float* bx = (const float*)d_in[3];  // (2,768)      fp32
    const float* bh = (const float*)d_in[4];  // (2,768)      fp32
    float* out = (float*)d_out;               // (32,4096,512) fp32
    _Float16* gxbuf = (_Float16*)d_ws;        // 100,663,296 fp16 = 201.3 MB

    // Phase 1: gx = x @ Wx^T + bx  (layout [b][l][t][768], fp16)
    gemm_gx_kernel<<<dim3(512, 12), 256, 0, stream>>>(x, Wx, bx, gxbuf);

    // Phase 2: 128 independent (b, l, dir) GRU chains
    gru_scan_kernel<<<dim3(128), 512, 0, stream>>>(Wh, bh, gxbuf, out);
}